// Round 16
// baseline (233.346 us; speedup 1.0000x reference)
//
#include <hip/hip_runtime.h>
#include <math.h>

using bf16x8 = __attribute__((ext_vector_type(8))) short;
using f32x4  = __attribute__((ext_vector_type(4))) float;
using f32x16 = __attribute__((ext_vector_type(16))) float;
using u16x4  = __attribute__((ext_vector_type(4))) unsigned short;
using u32x4  = __attribute__((ext_vector_type(4))) unsigned int;

#define DIMSZ 2048
#define NSEQ  2048
#define BATCH 2
#define NHEAD 16
#define HD    128

__device__ __forceinline__ unsigned short f2bf(float x) {
    unsigned int u = __builtin_bit_cast(unsigned int, x);
    unsigned int r = (u + 0x7FFFu + ((u >> 16) & 1u)) >> 16;
    return (unsigned short)r;
}

// packed RNE f32x2 -> bf16x2 (D.lo=cvt(S0), D.hi=cvt(S1))
__device__ __forceinline__ unsigned int cvtpk_bf16(float lo, float hi) {
    unsigned int r;
    asm("v_cvt_pk_bf16_f32 %0, %1, %2" : "=v"(r) : "v"(lo), "v"(hi));
    return r;
}

__device__ __forceinline__ void gload_lds16(const unsigned short* g, unsigned short* l) {
    __builtin_amdgcn_global_load_lds(
        (const __attribute__((address_space(1))) unsigned int*)g,
        (__attribute__((address_space(3))) unsigned int*)l, 16, 0, 0);
}

// ---------------- fused prep: cast x -> bf16 AND transpose+cast Wq|Wkv|Wo, ONE dispatch -------
#define NCAST 8192
__global__ void k_prep(const float* __restrict__ x, unsigned short* __restrict__ xb,
                       const float* __restrict__ Wq, const float* __restrict__ Wkv,
                       const float* __restrict__ Wo, unsigned short* __restrict__ wqkvt,
                       unsigned short* __restrict__ wot, float sc) {
    __shared__ float t[32][33];
    const int tid = threadIdx.x;
    if ((int)blockIdx.x < NCAST) {
        int i = blockIdx.x * 256 + tid;
        f32x4 v = *(const f32x4*)(x + (size_t)i * 4);
        u16x4 o;
#pragma unroll
        for (int j = 0; j < 4; j++) o[j] = f2bf(v[j]);
        *(u16x4*)(xb + (size_t)i * 4) = o;
        return;
    }
    const int tb = blockIdx.x - NCAST;
    const int ct = tb % 136;
    const int k0 = (tb / 136) * 32;
    const float* src;
    unsigned short* dst;
    float scale;
    int N, n0;
    if (ct < 64)      { src = Wq;  dst = wqkvt;                       scale = sc;   N = 2048; n0 = ct * 32; }
    else if (ct < 72) { src = Wkv; dst = wqkvt + (size_t)2048 * 2048; scale = 1.0f; N = 256;  n0 = (ct - 64) * 32; }
    else              { src = Wo;  dst = wot;                         scale = 1.0f; N = 2048; n0 = (ct - 72) * 32; }
    const int tx = tid & 31, ty = tid >> 5;
#pragma unroll
    for (int i = 0; i < 32; i += 8) t[ty + i][tx] = src[(size_t)(k0 + ty + i) * N + n0 + tx];
    __syncthreads();
#pragma unroll
    for (int i = 0; i < 32; i += 8)
        dst[(size_t)(n0 + ty + i) * 2048 + k0 + tx] = f2bf(t[tx][ty + i] * scale);
}

// XCD-bijective tile remap (T1): 1D grid, nwg % 8 == 0.
__device__ __forceinline__ void xcd_tile(int nbx, int& bx, int& by) {
    int wg = ((int)blockIdx.x & 7) * ((int)gridDim.x >> 3) + ((int)blockIdx.x >> 3);
    bx = wg % nbx;
    by = wg / nbx;
}

// ======== R16 GEMM: 128^2 tile, BK=64 (was 32) on the proven 2-phase dbuf skeleton ========
// Halves barrier/drain count per kernel (K/64 iterations); LDS 2x(16+16)=64KB still fits
// the pinned 2 blocks/CU. Staging: 4 chunks/tensor/thread, wave-uniform linear LDS dest.
// Fragments per kk-half at row*64 + kk*32 + g*8 (kk-outer loop keeps VGPR flat).
#define GEMM_BODY64(EPILOGUE)                                                                  \
    __shared__ unsigned short As[2][128 * 64];                                                 \
    __shared__ unsigned short Bs[2][128 * 64];                                                 \
    const int tid = threadIdx.x;                                                               \
    const int wid = tid >> 6;                                                                  \
    const int lane = tid & 63;                                                                 \
    const int g = lane >> 4, cc = lane & 15;                                                   \
    const int wr = wid >> 1, wc = wid & 1;                                                     \
    int bx, by;                                                                                \
    xcd_tile(nbx, bx, by);                                                                     \
    const size_t m0 = (size_t)by * 128;                                                        \
    const size_t n0 = (size_t)bx * 128;                                                        \
    f32x4 acc[4][4] = {};                                                                      \
    const unsigned short* gA = A + (m0 + wid * 32 + (lane >> 3)) * (size_t)K + (lane & 7) * 8; \
    const unsigned short* gB = Bt + (n0 + wid * 32 + (lane >> 3)) * (size_t)K + (lane & 7) * 8;\
    auto STAGE = [&](int buf, int k0) {                                                        \
        _Pragma("unroll") for (int c = 0; c < 4; c++) {                                        \
            gload_lds16(gA + (size_t)(c * 8) * K + k0, &As[buf][(wid * 32 + c * 8) * 64]);     \
            gload_lds16(gB + (size_t)(c * 8) * K + k0, &Bs[buf][(wid * 32 + c * 8) * 64]);     \
        }                                                                                      \
    };                                                                                         \
    STAGE(0, 0);                                                                               \
    __syncthreads();                                                                           \
    int cur = 0;                                                                               \
    for (int k0 = 0; k0 < K; k0 += 64) {                                                       \
        if (k0 + 64 < K) STAGE(cur ^ 1, k0 + 64);                                              \
        _Pragma("unroll") for (int kk = 0; kk < 2; kk++) {                                     \
            bf16x8 af[4], bfr[4];                                                              \
            _Pragma("unroll") for (int mi = 0; mi < 4; mi++)                                   \
                af[mi] = *(const bf16x8*)(&As[cur][(wr * 64 + mi * 16 + cc) * 64 + kk * 32 + g * 8]); \
            _Pragma("unroll") for (int ni = 0; ni < 4; ni++)                                   \
                bfr[ni] = *(const bf16x8*)(&Bs[cur][(wc * 64 + ni * 16 + cc) * 64 + kk * 32 + g * 8]); \
            _Pragma("unroll") for (int mi = 0; mi < 4; mi++)                                   \
                _Pragma("unroll") for (int ni = 0; ni < 4; ni++)                               \
                    acc[mi][ni] = __builtin_amdgcn_mfma_f32_16x16x32_bf16(af[mi], bfr[ni],     \
                                                                          acc[mi][ni], 0, 0, 0); \
        }                                                                                      \
        __syncthreads();                                                                       \
        cur ^= 1;                                                                              \
    }                                                                                          \
    EPILOGUE

// QKV GEMM + fused V^T epilogue (R15 proven epilogue split)
__global__ __launch_bounds__(256, 2)
void k_gemm_qkv(const unsigned short* __restrict__ A, const unsigned short* __restrict__ Bt,
                const float* __restrict__ bq, float bscale, const float* __restrict__ bkv,
                unsigned short* __restrict__ qout, unsigned short* __restrict__ kvout,
                unsigned short* __restrict__ vtout, int M, int K, int nbx) {
    GEMM_BODY64({
        if (n0 < 2048) {  // Q tile
            const int col0 = (int)n0 + wc * 64 + cc;
            float bia[4];
            _Pragma("unroll") for (int ni = 0; ni < 4; ni++) bia[ni] = bq[col0 + ni * 16] * bscale;
            _Pragma("unroll") for (int mi = 0; mi < 4; mi++) {
                size_t row = m0 + wr * 64 + mi * 16 + g * 4;
                _Pragma("unroll") for (int ni = 0; ni < 4; ni++)
                    _Pragma("unroll") for (int r = 0; r < 4; r++)
                        qout[(row + r) * 2048 + col0 + ni * 16] = f2bf(acc[mi][ni][r] + bia[ni]);
            }
        } else if (n0 < 2176) {  // K half of KV
            const int col0 = (int)n0 - 2048 + wc * 64 + cc;
            float bia[4];
            _Pragma("unroll") for (int ni = 0; ni < 4; ni++) bia[ni] = bkv[col0 + ni * 16];
            _Pragma("unroll") for (int mi = 0; mi < 4; mi++) {
                size_t row = m0 + wr * 64 + mi * 16 + g * 4;
                _Pragma("unroll") for (int ni = 0; ni < 4; ni++)
                    _Pragma("unroll") for (int r = 0; r < 4; r++)
                        kvout[(row + r) * 256 + col0 + ni * 16] = f2bf(acc[mi][ni][r] + bia[ni]);
            }
        } else {  // V half: write transposed straight to vt[b][d][n]
            const int col0 = (int)n0 - 2048 + wc * 64 + cc;  // [128, 256)
            float bia[4];
            _Pragma("unroll") for (int ni = 0; ni < 4; ni++) bia[ni] = bkv[col0 + ni * 16];
            _Pragma("unroll") for (int mi = 0; mi < 4; mi++) {
                size_t row = m0 + wr * 64 + mi * 16 + g * 4;  // 4-aligned; b uniform over r
                const int b = (int)(row >> 11);
                const int n = (int)(row & 2047);
                _Pragma("unroll") for (int ni = 0; ni < 4; ni++) {
                    const int d = col0 + ni * 16 - 128;
                    u16x4 o;
                    _Pragma("unroll") for (int r = 0; r < 4; r++) o[r] = f2bf(acc[mi][ni][r] + bia[ni]);
                    *(u16x4*)(vtout + ((size_t)(b * HD + d)) * NSEQ + n) = o;
                }
            }
        }
    })
}

// C[M,N] = A[M,K] * Bt[N,K]^T + bias (fp32 out)
__global__ __launch_bounds__(256, 2)
void k_gemm_bt_f32(const unsigned short* __restrict__ A, const unsigned short* __restrict__ Bt,
                   const float* __restrict__ bias, float* __restrict__ Cout,
                   int M, int N, int K, int nbx) {
    GEMM_BODY64({
        const int col0 = (int)n0 + wc * 64 + cc;
        float bia[4];
        _Pragma("unroll") for (int ni = 0; ni < 4; ni++) bia[ni] = bias[col0 + ni * 16];
        _Pragma("unroll") for (int mi = 0; mi < 4; mi++) {
            size_t row = m0 + wr * 64 + mi * 16 + g * 4;
            _Pragma("unroll") for (int ni = 0; ni < 4; ni++)
                _Pragma("unroll") for (int r = 0; r < 4; r++)
                    Cout[(row + r) * N + col0 + ni * 16] = acc[mi][ni][r] + bia[ni];
        }
    })
}

// ---------------- flash attention: EXACT R11 kernel (measured 82.0 us, VGPR 112) ----------------
__global__ __launch_bounds__(256, 2)
void k_attn(const unsigned short* __restrict__ q, const unsigned short* __restrict__ kvp,
            const unsigned short* __restrict__ vt, unsigned short* __restrict__ out) {
    __shared__ unsigned char Kb[2][16384];
    __shared__ unsigned char Vb[2][16384];

    const int b = blockIdx.z, h = blockIdx.y, qt = blockIdx.x;
    const int tid = threadIdx.x, w = tid >> 6, lane = tid & 63;
    const int q32 = lane & 31, hi = lane >> 5;

    const int qrow = qt * 128 + w * 32 + q32;
    const unsigned short* qp = q + (size_t)(b * NSEQ + qrow) * DIMSZ + h * HD + hi * 8;
    bf16x8 qf[8];
#pragma unroll
    for (int dc = 0; dc < 8; dc++) qf[dc] = *(const bf16x8*)(qp + dc * 16);

    const char* kvpc = (const char*)kvp;
    const char* vtc  = (const char*)vt;
    size_t srcK[4], srcV[4];
#pragma unroll
    for (int c = 0; c < 4; c++) {
        unsigned int o = (tid + c * 256) * 16;
        unsigned int krow = o >> 8, kcol = o & 255;
        srcK[c] = (size_t)(b * NSEQ + krow) * 512 + (kcol ^ (((krow >> 1) & 15) << 4));
        unsigned int vrow = o >> 7, vcol = o & 127;
        srcV[c] = (size_t)(b * HD + vrow) * 4096 + (vcol ^ (((vrow >> 2) & 7) << 4));
    }

    auto STAGE = [&](int buf, int t) {
        size_t kb_ = (size_t)t * 32768;
        size_t vb_ = (size_t)t * 128;
#pragma unroll
        for (int c = 0; c < 4; c++) {
            gload_lds16((const unsigned short*)(kvpc + srcK[c] + kb_),
                        (unsigned short*)(Kb[buf] + (w * 64 + c * 256) * 16));
            gload_lds16((const unsigned short*)(vtc + srcV[c] + vb_),
                        (unsigned short*)(Vb[buf] + (w * 64 + c * 256) * 16));
        }
    };

    f32x16 o0 = {}, o1 = {}, o2 = {}, o3 = {};
    float l_run = 0.0f;
    const unsigned int swK = ((q32 >> 1) & 15) << 4;
    const unsigned int swV = ((q32 >> 2) & 7) << 4;

#define PROC_KT(S, KTB)                                                               \
    {                                                                                 \
        float pz[16];                                                                 \
        _Pragma("unroll") for (int r = 0; r < 16; r++) {                              \
            pz[r] = __builtin_amdgcn_exp2f(S[r]);                                     \
            l_run += pz[r];                                                           \
        }                                                                             \
        _Pragma("unroll") for (int kc = 0; kc < 2; kc++) {                            \
            unsigned int own01 = cvtpk_bf16(pz[kc * 8 + 0], pz[kc * 8 + 1]);          \
            unsigned int own23 = cvtpk_bf16(pz[kc * 8 + 2], pz[kc * 8 + 3]);          \
            unsigned int own45 = cvtpk_bf16(pz[kc * 8 + 4], pz[kc * 8 + 5]);          \
            unsigned int own67 = cvtpk_bf16(pz[kc * 8 + 6], pz[kc * 8 + 7]);          \
            unsigned int send_a = hi ? own01 : own45;                                 \
            unsigned int send_b = hi ? own23 : own67;                                 \
            unsigned int got_a = (unsigned int)__shfl_xor((int)send_a, 32, 64);       \
            unsigned int got_b = (unsigned int)__shfl_xor((int)send_b, 32, 64);       \
            u32x4 awv;                                                                \
            awv[0] = hi ? got_a : own01;                                              \
            awv[1] = hi ? got_b : own23;                                              \
            awv[2] = hi ? own45 : got_a;                                              \
            awv[3] = hi ? own67 : got_b;                                              \
            bf16x8 pa = __builtin_bit_cast(bf16x8, awv);                              \
            const unsigned int kbo = (KTB) + kc * 32 + hi * 16;                       \
            bf16x8 vf0 = *(const bf16x8*)(Vc + (q32 + 0) * 128 + (kbo ^ swV));        \
            bf16x8 vf1 = *(const bf16x8*)(Vc + (q32 + 32) * 128 + (kbo ^ swV));       \
            bf16x8 vf2 = *(const bf16x8*)(Vc + (q32 + 64) * 128 + (kbo ^ swV));       \
            bf16x8 vf3 = *(const bf16x8*)(Vc + (q32 + 96) * 128 + (kbo ^ swV));       \
            __builtin_amdgcn_s_setprio(1);                                            \
            o0 = __builtin_amdgcn_mfma_f32_32x32x16_bf16(pa, vf0, o0, 0, 0, 0);       \
            o1 = __builtin_amdgcn_mfma_f32_32x32x16_bf16(pa, vf1, o1, 0, 0, 0);       \
            o2 = __builtin_amdgcn_mfma_f32_32x32x16_bf16(pa, vf2, o2, 0, 0, 0);       \
            o3 = __builtin_amdgcn_mfma_f32_32x32x16_bf16(pa, vf3, o3, 0, 0, 0);       \
            __builtin_amdgcn_s_setprio(0);                                            \
        }                                                                             \
    }

    STAGE(0, 0);
    __syncthreads();

    for (int t = 0; t < NSEQ / 64; t++) {
        const int cur = t & 1;
        if (t < NSEQ / 64 - 1) STAGE(cur ^ 1, t + 1);

        const unsigned char* Kc = Kb[cur];
        const unsigned char* Vc = Vb[cur];

        f32x16 s0 = {}, s1 = {};
#pragma unroll
        for (int dc = 0; dc < 8; dc++) {
            const unsigned int db = dc * 32 + hi * 16;
            bf16x8 kf0 = *(const bf16x8*)(Kc + q32 * 256 + (db ^ swK));
            bf16x8 kf1 = *(const bf16x8*)(Kc + (q32 + 32) * 256 + (db ^ swK));
            __builtin_amdgcn_s_setprio(1);
            s0 = __builtin_amdgcn_mfma_f32_32x32x16_bf16(kf0, qf[dc], s0, 0, 0, 0);
            s1 = __builtin_amdgcn_mfma_f32_32x32x16_bf16(kf1, qf[dc], s1, 0, 0, 0);
            __builtin_amdgcn_s_setprio(0);
        }

        PROC_KT(s0, 0)
        PROC_KT(s1, 64)

        __syncthreads();
    }
#undef PROC_KT

    l_run += __shfl_xor(l_run, 32, 64);
    float* Lp = (float*)(Kb[0] + w * 128);
    if (hi == 0) Lp[q32] = l_run;

    float rinv[16];
#pragma unroll
    for (int r = 0; r < 16; r++) {
        int qloc = (r & 3) + 8 * (r >> 2) + 4 * hi;
        rinv[r] = 1.0f / Lp[qloc];
    }

    unsigned short* op = out + (size_t)(b * NSEQ + qt * 128 + w * 32) * DIMSZ + h * HD + q32;
#pragma unroll
    for (int r = 0; r < 16; r++) {
        int qloc = (r & 3) + 8 * (r >> 2) + 4 * hi;
        op[(size_t)qloc * DIMSZ + 0]  = f2bf(o0[r] * rinv[r]);
        op[(size_t)qloc * DIMSZ + 32] = f2bf(o1[r] * rinv[r]);
        op[(size_t)qloc * DIMSZ + 64] = f2bf(o2[r] * rinv[r]);
        op[(size_t)qloc * DIMSZ + 96] = f2bf(o3[r] * rinv[r]);
    }
}

extern "C" void kernel_launch(void* const* d_in, const int* in_sizes, int n_in,
                              void* d_out, int out_size, void* d_ws, size_t ws_size,
                              hipStream_t stream) {
    const float* x   = (const float*)d_in[0];
    const float* Wq  = (const float*)d_in[1];
    const float* bq  = (const float*)d_in[2];
    const float* Wkv = (const float*)d_in[3];
    const float* bkv = (const float*)d_in[4];
    const float* Wo  = (const float*)d_in[5];
    const float* bo  = (const float*)d_in[6];

    char* w = (char*)d_ws;
    unsigned short* xb    = (unsigned short*)(w);              // 16,777,216 B (x bf16) -- reused as attn out
    unsigned short* wqkvt = (unsigned short*)(w + 16777216);   //  9,437,184 B (2304 x 2048 bf16)
    unsigned short* wot   = (unsigned short*)(w + 26214400);   //  8,388,608 B
    unsigned short* qb    = (unsigned short*)(w + 34603008);   // 16,777,216 B
    unsigned short* kvpb  = (unsigned short*)(w + 51380224);   //  2,097,152 B (K half used)
    unsigned short* vtb   = (unsigned short*)(w + 53477376);   //  1,048,576 B
    unsigned short* aob   = xb;                                // alias: x consumed before attention writes

    const float sc = 0.08838834764831845f * 1.4426950408889634f;  // 1/sqrt(128) * log2(e)

    // 1) fused prep: cast x (8192 blocks) + transpose Wq/Wkv/Wo (8704 blocks), one dispatch
    k_prep<<<dim3(NCAST + 136 * 64), dim3(256), 0, stream>>>(x, xb, Wq, Wkv, Wo, wqkvt, wot, sc);

    // 2) fused QKV = x @ [Wq|Wkv] (+bias); BK=64 GEMM; V half written transposed straight to vtb
    k_gemm_qkv<<<dim3((2304 / 128) * (BATCH * NSEQ / 128)), dim3(256), 0, stream>>>(
        xb, wqkvt, bq, sc, bkv, qb, kvpb, vtb, BATCH * NSEQ, DIMSZ, 2304 / 128);
    // 3) attention (exact R11: 4 waves x 32 q-rows, KVBLK=64, 512 blocks = 2/CU)
    k_attn<<<dim3(NSEQ / 128, NHEAD, BATCH), dim3(256), 0, stream>>>(qb, kvpb, vtb, aob);
    // 4) out = attn @ Wo + bo (fp32 out); BK=64 GEMM; XCD-swizzled 1D grid (512 = 64*8)
    k_gemm_bt_f32<<<dim3((DIMSZ / 128) * (BATCH * NSEQ / 128)), dim3(256), 0, stream>>>(
        aob, wot, bo, (float*)d_out, BATCH * NSEQ, DIMSZ, DIMSZ, DIMSZ / 128);
}

// Round 17
// 191.132 us; speedup vs baseline: 1.2209x; 1.2209x over previous
//
#include <hip/hip_runtime.h>
#include <math.h>

using bf16x8 = __attribute__((ext_vector_type(8))) short;
using f32x4  = __attribute__((ext_vector_type(4))) float;
using f32x16 = __attribute__((ext_vector_type(16))) float;
using u16x4  = __attribute__((ext_vector_type(4))) unsigned short;
using u32x4  = __attribute__((ext_vector_type(4))) unsigned int;

#define DIMSZ 2048
#define NSEQ  2048
#define BATCH 2
#define NHEAD 16
#define HD    128

__device__ __forceinline__ unsigned short f2bf(float x) {
    unsigned int u = __builtin_bit_cast(unsigned int, x);
    unsigned int r = (u + 0x7FFFu + ((u >> 16) & 1u)) >> 16;
    return (unsigned short)r;
}

// packed RNE f32x2 -> bf16x2 (D.lo=cvt(S0), D.hi=cvt(S1))
__device__ __forceinline__ unsigned int cvtpk_bf16(float lo, float hi) {
    unsigned int r;
    asm("v_cvt_pk_bf16_f32 %0, %1, %2" : "=v"(r) : "v"(lo), "v"(hi));
    return r;
}

__device__ __forceinline__ void gload_lds16(const unsigned short* g, unsigned short* l) {
    __builtin_amdgcn_global_load_lds(
        (const __attribute__((address_space(1))) unsigned int*)g,
        (__attribute__((address_space(3))) unsigned int*)l, 16, 0, 0);
}

// ---------------- fused prep: cast x -> bf16 AND transpose+cast Wq|Wkv|Wo, ONE dispatch -------
#define NCAST 8192
__global__ void k_prep(const float* __restrict__ x, unsigned short* __restrict__ xb,
                       const float* __restrict__ Wq, const float* __restrict__ Wkv,
                       const float* __restrict__ Wo, unsigned short* __restrict__ wqkvt,
                       unsigned short* __restrict__ wot, float sc) {
    __shared__ float t[32][33];
    const int tid = threadIdx.x;
    if ((int)blockIdx.x < NCAST) {
        int i = blockIdx.x * 256 + tid;
        f32x4 v = *(const f32x4*)(x + (size_t)i * 4);
        u16x4 o;
#pragma unroll
        for (int j = 0; j < 4; j++) o[j] = f2bf(v[j]);
        *(u16x4*)(xb + (size_t)i * 4) = o;
        return;
    }
    const int tb = blockIdx.x - NCAST;
    const int ct = tb % 136;
    const int k0 = (tb / 136) * 32;
    const float* src;
    unsigned short* dst;
    float scale;
    int N, n0;
    if (ct < 64)      { src = Wq;  dst = wqkvt;                       scale = sc;   N = 2048; n0 = ct * 32; }
    else if (ct < 72) { src = Wkv; dst = wqkvt + (size_t)2048 * 2048; scale = 1.0f; N = 256;  n0 = (ct - 64) * 32; }
    else              { src = Wo;  dst = wot;                         scale = 1.0f; N = 2048; n0 = (ct - 72) * 32; }
    const int tx = tid & 31, ty = tid >> 5;
#pragma unroll
    for (int i = 0; i < 32; i += 8) t[ty + i][tx] = src[(size_t)(k0 + ty + i) * N + n0 + tx];
    __syncthreads();
#pragma unroll
    for (int i = 0; i < 32; i += 8)
        dst[(size_t)(n0 + ty + i) * 2048 + k0 + tx] = f2bf(t[tx][ty + i] * scale);
}

// XCD-bijective tile remap (T1): 1D grid, nwg % 8 == 0.
__device__ __forceinline__ void xcd_tile(int nbx, int& bx, int& by) {
    int wg = ((int)blockIdx.x & 7) * ((int)gridDim.x >> 3) + ((int)blockIdx.x >> 3);
    bx = wg % nbx;
    by = wg / nbx;
}

// ---------------- k_gemm_qkv: EXACT R15 kernel (BK=32 2-phase, proven ~52 us) ----------------
__global__ __launch_bounds__(256, 2)
void k_gemm_qkv(const unsigned short* __restrict__ A, const unsigned short* __restrict__ Bt,
                const float* __restrict__ bq, float bscale, const float* __restrict__ bkv,
                unsigned short* __restrict__ qout, unsigned short* __restrict__ kvout,
                unsigned short* __restrict__ vtout, int M, int K, int nbx) {
    __shared__ unsigned short As[2][128 * 32];
    __shared__ unsigned short Bs[2][128 * 32];
    const int tid = threadIdx.x;
    const int wid = tid >> 6;
    const int lane = tid & 63;
    const int g = lane >> 4, cc = lane & 15;
    const int wr = wid >> 1, wc = wid & 1;
    int bx, by;
    xcd_tile(nbx, bx, by);
    const size_t m0 = (size_t)by * 128;
    const size_t n0 = (size_t)bx * 128;

    f32x4 acc[4][4] = {};

    const int srow = wid * 32 + (lane >> 2);
    const int sch = lane & 3;
    const unsigned short* gA = A + (m0 + srow) * (size_t)K + sch * 8;
    const unsigned short* gB = Bt + (n0 + srow) * (size_t)K + sch * 8;
    const int lo = wid * 32 * 32;

    auto STAGE = [&](int buf, int k0) {
        gload_lds16(gA + k0, &As[buf][lo]);
        gload_lds16(gA + 16 * (size_t)K + k0, &As[buf][lo + 16 * 32]);
        gload_lds16(gB + k0, &Bs[buf][lo]);
        gload_lds16(gB + 16 * (size_t)K + k0, &Bs[buf][lo + 16 * 32]);
    };

    STAGE(0, 0);
    __syncthreads();
    int cur = 0;
    for (int k0 = 0; k0 < K; k0 += 32) {
        if (k0 + 32 < K) STAGE(cur ^ 1, k0 + 32);
        bf16x8 af[4], bfr[4];
#pragma unroll
        for (int mi = 0; mi < 4; mi++) af[mi] = *(const bf16x8*)(&As[cur][(wr * 64 + mi * 16 + cc) * 32 + g * 8]);
#pragma unroll
        for (int ni = 0; ni < 4; ni++) bfr[ni] = *(const bf16x8*)(&Bs[cur][(wc * 64 + ni * 16 + cc) * 32 + g * 8]);
#pragma unroll
        for (int mi = 0; mi < 4; mi++)
#pragma unroll
            for (int ni = 0; ni < 4; ni++)
                acc[mi][ni] = __builtin_amdgcn_mfma_f32_16x16x32_bf16(af[mi], bfr[ni], acc[mi][ni], 0, 0, 0);
        __syncthreads();
        cur ^= 1;
    }

    if (n0 < 2048) {  // Q tile
        const int col0 = (int)n0 + wc * 64 + cc;
        float bia[4];
#pragma unroll
        for (int ni = 0; ni < 4; ni++) bia[ni] = bq[col0 + ni * 16] * bscale;
#pragma unroll
        for (int mi = 0; mi < 4; mi++) {
            size_t row = m0 + wr * 64 + mi * 16 + g * 4;
#pragma unroll
            for (int ni = 0; ni < 4; ni++)
#pragma unroll
                for (int r = 0; r < 4; r++)
                    qout[(row + r) * 2048 + col0 + ni * 16] = f2bf(acc[mi][ni][r] + bia[ni]);
        }
    } else if (n0 < 2176) {  // K half of KV
        const int col0 = (int)n0 - 2048 + wc * 64 + cc;
        float bia[4];
#pragma unroll
        for (int ni = 0; ni < 4; ni++) bia[ni] = bkv[col0 + ni * 16];
#pragma unroll
        for (int mi = 0; mi < 4; mi++) {
            size_t row = m0 + wr * 64 + mi * 16 + g * 4;
#pragma unroll
            for (int ni = 0; ni < 4; ni++)
#pragma unroll
                for (int r = 0; r < 4; r++)
                    kvout[(row + r) * 256 + col0 + ni * 16] = f2bf(acc[mi][ni][r] + bia[ni]);
        }
    } else {  // V half: write transposed to vt[b][d][n]
        const int col0 = (int)n0 - 2048 + wc * 64 + cc;  // [128, 256)
        float bia[4];
#pragma unroll
        for (int ni = 0; ni < 4; ni++) bia[ni] = bkv[col0 + ni * 16];
#pragma unroll
        for (int mi = 0; mi < 4; mi++) {
            size_t row = m0 + wr * 64 + mi * 16 + g * 4;   // 4-aligned; b uniform over r
            const int b = (int)(row >> 11);
            const int n = (int)(row & 2047);
#pragma unroll
            for (int ni = 0; ni < 4; ni++) {
                const int d = col0 + ni * 16 - 128;
                u16x4 o;
#pragma unroll
                for (int r = 0; r < 4; r++) o[r] = f2bf(acc[mi][ni][r] + bia[ni]);
                *(u16x4*)(vtout + ((size_t)(b * HD + d)) * NSEQ + n) = o;
            }
        }
    }
}

// ---------------- k_gemm_bt_f32: BK=64 + T2 XOR-swizzle (A/B experiment vs qkv's BK=32) -------
// LDS rows are 128 B (8 granules). Swizzle: granule' = granule ^ (row&7) (bijective).
// Staging: linear LDS dest (T21), inverse-swizzled global source granule (lane&7)^(lane>>3)
// (row&7 == lane>>3 since chunk bases are multiples of 8). Read: byte = row*128 +
// ((kk*4+g)^(row&7))*16. Bank check: per (cc&7)-class 8 lanes spread over 4 granules x 2 = free.
__global__ __launch_bounds__(256, 2)
void k_gemm_bt_f32(const unsigned short* __restrict__ A, const unsigned short* __restrict__ Bt,
                   const float* __restrict__ bias, float* __restrict__ Cout,
                   int M, int N, int K, int nbx) {
    __shared__ unsigned short As[2][128 * 64];
    __shared__ unsigned short Bs[2][128 * 64];
    const int tid = threadIdx.x;
    const int wid = tid >> 6;
    const int lane = tid & 63;
    const int g = lane >> 4, cc = lane & 15;
    const int wr = wid >> 1, wc = wid & 1;
    int bx, by;
    xcd_tile(nbx, bx, by);
    const size_t m0 = (size_t)by * 128;
    const size_t n0 = (size_t)bx * 128;

    f32x4 acc[4][4] = {};

    const int srow = wid * 32 + (lane >> 3);
    const int sgran = (lane & 7) ^ (lane >> 3);  // inverse-swizzled source granule
    const unsigned short* gA = A + (m0 + srow) * (size_t)K + sgran * 8;
    const unsigned short* gB = Bt + (n0 + srow) * (size_t)K + sgran * 8;

    auto STAGE = [&](int buf, int k0) {
#pragma unroll
        for (int c = 0; c < 4; c++) {
            gload_lds16(gA + (size_t)(c * 8) * K + k0, &As[buf][(wid * 32 + c * 8) * 64]);
            gload_lds16(gB + (size_t)(c * 8) * K + k0, &Bs[buf][(wid * 32 + c * 8) * 64]);
        }
    };

    STAGE(0, 0);
    __syncthreads();
    int cur = 0;
    for (int k0 = 0; k0 < K; k0 += 64) {
        if (k0 + 64 < K) STAGE(cur ^ 1, k0 + 64);
#pragma unroll
        for (int kk = 0; kk < 2; kk++) {
            bf16x8 af[4], bfr[4];
#pragma unroll
            for (int mi = 0; mi < 4; mi++) {
                const int row = wr * 64 + mi * 16 + cc;
                af[mi] = *(const bf16x8*)((const unsigned char*)&As[cur][0] +
                                          row * 128 + (((kk * 4 + g) ^ (row & 7)) * 16));
            }
#pragma unroll
            for (int ni = 0; ni < 4; ni++) {
                const int row = wc * 64 + ni * 16 + cc;
                bfr[ni] = *(const bf16x8*)((const unsigned char*)&Bs[cur][0] +
                                           row * 128 + (((kk * 4 + g) ^ (row & 7)) * 16));
            }
#pragma unroll
            for (int mi = 0; mi < 4; mi++)
#pragma unroll
                for (int ni = 0; ni < 4; ni++)
                    acc[mi][ni] = __builtin_amdgcn_mfma_f32_16x16x32_bf16(af[mi], bfr[ni], acc[mi][ni], 0, 0, 0);
        }
        __syncthreads();
        cur ^= 1;
    }

    const int col0 = (int)n0 + wc * 64 + cc;
    float bia[4];
#pragma unroll
    for (int ni = 0; ni < 4; ni++) bia[ni] = bias[col0 + ni * 16];
#pragma unroll
    for (int mi = 0; mi < 4; mi++) {
        size_t row = m0 + wr * 64 + mi * 16 + g * 4;
#pragma unroll
        for (int ni = 0; ni < 4; ni++)
#pragma unroll
            for (int r = 0; r < 4; r++)
                Cout[(row + r) * N + col0 + ni * 16] = acc[mi][ni][r] + bia[ni];
    }
}

// ---------------- flash attention: EXACT R11 kernel (measured 82.0 us, VGPR 112) ----------------
__global__ __launch_bounds__(256, 2)
void k_attn(const unsigned short* __restrict__ q, const unsigned short* __restrict__ kvp,
            const unsigned short* __restrict__ vt, unsigned short* __restrict__ out) {
    __shared__ unsigned char Kb[2][16384];
    __shared__ unsigned char Vb[2][16384];

    const int b = blockIdx.z, h = blockIdx.y, qt = blockIdx.x;
    const int tid = threadIdx.x, w = tid >> 6, lane = tid & 63;
    const int q32 = lane & 31, hi = lane >> 5;

    const int qrow = qt * 128 + w * 32 + q32;
    const unsigned short* qp = q + (size_t)(b * NSEQ + qrow) * DIMSZ + h * HD + hi * 8;
    bf16x8 qf[8];
#pragma unroll
    for (int dc = 0; dc < 8; dc++) qf[dc] = *(const bf16x8*)(qp + dc * 16);

    const char* kvpc = (const char*)kvp;
    const char* vtc  = (const char*)vt;
    size_t srcK[4], srcV[4];
#pragma unroll
    for (int c = 0; c < 4; c++) {
        unsigned int o = (tid + c * 256) * 16;
        unsigned int krow = o >> 8, kcol = o & 255;
        srcK[c] = (size_t)(b * NSEQ + krow) * 512 + (kcol ^ (((krow >> 1) & 15) << 4));
        unsigned int vrow = o >> 7, vcol = o & 127;
        srcV[c] = (size_t)(b * HD + vrow) * 4096 + (vcol ^ (((vrow >> 2) & 7) << 4));
    }

    auto STAGE = [&](int buf, int t) {
        size_t kb_ = (size_t)t * 32768;
        size_t vb_ = (size_t)t * 128;
#pragma unroll
        for (int c = 0; c < 4; c++) {
            gload_lds16((const unsigned short*)(kvpc + srcK[c] + kb_),
                        (unsigned short*)(Kb[buf] + (w * 64 + c * 256) * 16));
            gload_lds16((const unsigned short*)(vtc + srcV[c] + vb_),
                        (unsigned short*)(Vb[buf] + (w * 64 + c * 256) * 16));
        }
    };

    f32x16 o0 = {}, o1 = {}, o2 = {}, o3 = {};
    float l_run = 0.0f;
    const unsigned int swK = ((q32 >> 1) & 15) << 4;
    const unsigned int swV = ((q32 >> 2) & 7) << 4;

#define PROC_KT(S, KTB)                                                               \
    {                                                                                 \
        float pz[16];                                                                 \
        _Pragma("unroll") for (int r = 0; r < 16; r++) {                              \
            pz[r] = __builtin_amdgcn_exp2f(S[r]);                                     \
            l_run += pz[r];                                                           \
        }                                                                             \
        _Pragma("unroll") for (int kc = 0; kc < 2; kc++) {                            \
            unsigned int own01 = cvtpk_bf16(pz[kc * 8 + 0], pz[kc * 8 + 1]);          \
            unsigned int own23 = cvtpk_bf16(pz[kc * 8 + 2], pz[kc * 8 + 3]);          \
            unsigned int own45 = cvtpk_bf16(pz[kc * 8 + 4], pz[kc * 8 + 5]);          \
            unsigned int own67 = cvtpk_bf16(pz[kc * 8 + 6], pz[kc * 8 + 7]);          \
            unsigned int send_a = hi ? own01 : own45;                                 \
            unsigned int send_b = hi ? own23 : own67;                                 \
            unsigned int got_a = (unsigned int)__shfl_xor((int)send_a, 32, 64);       \
            unsigned int got_b = (unsigned int)__shfl_xor((int)send_b, 32, 64);       \
            u32x4 awv;                                                                \
            awv[0] = hi ? got_a : own01;                                              \
            awv[1] = hi ? got_b : own23;                                              \
            awv[2] = hi ? own45 : got_a;                                              \
            awv[3] = hi ? own67 : got_b;                                              \
            bf16x8 pa = __builtin_bit_cast(bf16x8, awv);                              \
            const unsigned int kbo = (KTB) + kc * 32 + hi * 16;                       \
            bf16x8 vf0 = *(const bf16x8*)(Vc + (q32 + 0) * 128 + (kbo ^ swV));        \
            bf16x8 vf1 = *(const bf16x8*)(Vc + (q32 + 32) * 128 + (kbo ^ swV));       \
            bf16x8 vf2 = *(const bf16x8*)(Vc + (q32 + 64) * 128 + (kbo ^ swV));       \
            bf16x8 vf3 = *(const bf16x8*)(Vc + (q32 + 96) * 128 + (kbo ^ swV));       \
            __builtin_amdgcn_s_setprio(1);                                            \
            o0 = __builtin_amdgcn_mfma_f32_32x32x16_bf16(pa, vf0, o0, 0, 0, 0);       \
            o1 = __builtin_amdgcn_mfma_f32_32x32x16_bf16(pa, vf1, o1, 0, 0, 0);       \
            o2 = __builtin_amdgcn_mfma_f32_32x32x16_bf16(pa, vf2, o2, 0, 0, 0);       \
            o3 = __builtin_amdgcn_mfma_f32_32x32x16_bf16(pa, vf3, o3, 0, 0, 0);       \
            __builtin_amdgcn_s_setprio(0);                                            \
        }                                                                             \
    }

    STAGE(0, 0);
    __syncthreads();

    for (int t = 0; t < NSEQ / 64; t++) {
        const int cur = t & 1;
        if (t < NSEQ / 64 - 1) STAGE(cur ^ 1, t + 1);

        const unsigned char* Kc = Kb[cur];
        const unsigned char* Vc = Vb[cur];

        f32x16 s0 = {}, s1 = {};
#pragma unroll
        for (int dc = 0; dc < 8; dc++) {
            const unsigned int db = dc * 32 + hi * 16;
            bf16x8 kf0 = *(const bf16x8*)(Kc + q32 * 256 + (db ^ swK));
            bf16x8 kf1 = *(const bf16x8*)(Kc + (q32 + 32) * 256 + (db ^ swK));
            __builtin_amdgcn_s_setprio(1);
            s0 = __builtin_amdgcn_mfma_f32_32x32x16_bf16(kf0, qf[dc], s0, 0, 0, 0);
            s1 = __builtin_amdgcn_mfma_f32_32x32x16_bf16(kf1, qf[dc], s1, 0, 0, 0);
            __builtin_amdgcn_s_setprio(0);
        }

        PROC_KT(s0, 0)
        PROC_KT(s1, 64)

        __syncthreads();
    }
#undef PROC_KT

    l_run += __shfl_xor(l_run, 32, 64);
    float* Lp = (float*)(Kb[0] + w * 128);
    if (hi == 0) Lp[q32] = l_run;

    float rinv[16];
#pragma unroll
    for (int r = 0; r < 16; r++) {
        int qloc = (r & 3) + 8 * (r >> 2) + 4 * hi;
        rinv[r] = 1.0f / Lp[qloc];
    }

    unsigned short* op = out + (size_t)(b * NSEQ + qt * 128 + w * 32) * DIMSZ + h * HD + q32;
#pragma unroll
    for (int r = 0; r < 16; r++) {
        int qloc = (r & 3) + 8 * (r >> 2) + 4 * hi;
        op[(size_t)qloc * DIMSZ + 0]  = f2bf(o0[r] * rinv[r]);
        op[(size_t)qloc * DIMSZ + 32] = f2bf(o1[r] * rinv[r]);
        op[(size_t)qloc * DIMSZ + 64] = f2bf(o2[r] * rinv[r]);
        op[(size_t)qloc * DIMSZ + 96] = f2bf(o3[r] * rinv[r]);
    }
}

extern "C" void kernel_launch(void* const* d_in, const int* in_sizes, int n_in,
                              void* d_out, int out_size, void* d_ws, size_t ws_size,
                              hipStream_t stream) {
    const float* x   = (const float*)d_in[0];
    const float* Wq  = (const float*)d_in[1];
    const float* bq  = (const float*)d_in[2];
    const float* Wkv = (const float*)d_in[3];
    const float* bkv = (const float*)d_in[4];
    const float* Wo  = (const float*)d_in[5];
    const float* bo  = (const float*)d_in[6];

    char* w = (char*)d_ws;
    unsigned short* xb    = (unsigned short*)(w);              // 16,777,216 B (x bf16) -- reused as attn out
    unsigned short* wqkvt = (unsigned short*)(w + 16777216);   //  9,437,184 B (2304 x 2048 bf16)
    unsigned short* wot   = (unsigned short*)(w + 26214400);   //  8,388,608 B
    unsigned short* qb    = (unsigned short*)(w + 34603008);   // 16,777,216 B
    unsigned short* kvpb  = (unsigned short*)(w + 51380224);   //  2,097,152 B (K half used)
    unsigned short* vtb   = (unsigned short*)(w + 53477376);   //  1,048,576 B
    unsigned short* aob   = xb;                                // alias: x consumed before attention writes

    const float sc = 0.08838834764831845f * 1.4426950408889634f;  // 1/sqrt(128) * log2(e)

    // 1) fused prep: cast x (8192 blocks) + transpose Wq/Wkv/Wo (8704 blocks), one dispatch
    k_prep<<<dim3(NCAST + 136 * 64), dim3(256), 0, stream>>>(x, xb, Wq, Wkv, Wo, wqkvt, wot, sc);

    // 2) fused QKV (R15 BK=32 kernel); V half written transposed straight to vtb
    k_gemm_qkv<<<dim3((2304 / 128) * (BATCH * NSEQ / 128)), dim3(256), 0, stream>>>(
        xb, wqkvt, bq, sc, bkv, qb, kvpb, vtb, BATCH * NSEQ, DIMSZ, 2304 / 128);
    // 3) attention (exact R11)
    k_attn<<<dim3(NSEQ / 128, NHEAD, BATCH), dim3(256), 0, stream>>>(qb, kvpb, vtb, aob);
    // 4) out = attn @ Wo + bo (fp32 out); BK=64 + swizzle experiment
    k_gemm_bt_f32<<<dim3((DIMSZ / 128) * (BATCH * NSEQ / 128)), dim3(256), 0, stream>>>(
        aob, wot, bo, (float*)d_out, BATCH * NSEQ, DIMSZ, DIMSZ, DIMSZ / 128);
}